// Round 1
// baseline (693.677 us; speedup 1.0000x reference)
//
#include <hip/hip_runtime.h>
#include <math.h>

#define BH   32      // b*h
#define NSEQ 2048
#define DH   64
#define NH   16

// ---------------- prep: l2norm * scale -> RoPE -> (optional) fold 1/sqrt(d) ----
// one wave (64 lanes) per row of length 64; block = 256 threads = 4 rows
__global__ void prep_kernel(const float* __restrict__ in, const float* __restrict__ scale,
                            float* __restrict__ out, float smul) {
    int row  = blockIdx.x * 4 + (threadIdx.x >> 6);
    int lane = threadIdx.x & 63;
    size_t base = (size_t)row * DH;
    float x = in[base + lane];
    float ss = x * x;
    #pragma unroll
    for (int off = 32; off > 0; off >>= 1) ss += __shfl_xor(ss, off);
    float inv = 1.0f / fmaxf(sqrtf(ss), 1e-12f);
    float t = x * inv * scale[lane];
    // rotate_half: (-x2, x1); partner is lane^32, sign negative for low half
    float partner = __shfl_xor(t, 32);
    float rot = (lane < 32) ? -partner : partner;
    int p = lane & 31;
    float inv_freq = powf(10000.0f, -(float)p / 32.0f);
    int pos = row & (NSEQ - 1);
    float theta = (float)pos * inv_freq;
    float sn, cs;
    sincosf(theta, &sn, &cs);   // accurate libm version: theta up to ~2047
    out[base + lane] = (t * cs + rot * sn) * smul;
}

// ---------------- flash attention, fp32, online softmax ----------------------
// WG = 256 threads = 4 waves; WG handles 64 q rows of one (b,h); wave w -> rows w*16..w*16+15
// lane: rg = lane&3 (4 rows), cg = lane>>2 (4 keys in scores / 4 dims in PV)
// LDS: Qt[dim][row], Kt[dim][key], Vs[key][dim], Ps[key][row]  (all 64x64 f32, 16KB each)
__launch_bounds__(256, 2)
__global__ void attn_kernel(const float* __restrict__ qp, const float* __restrict__ kp,
                            const float* __restrict__ vp, float* __restrict__ out) {
    __shared__ __align__(16) float Qt[64 * 64];
    __shared__ __align__(16) float Kt[64 * 64];
    __shared__ __align__(16) float Vs[64 * 64];
    __shared__ __align__(16) float Ps[64 * 64];

    const int bh   = blockIdx.y;
    const int tile = blockIdx.x;
    const int tid  = threadIdx.x;
    const int w    = tid >> 6;
    const int lane = tid & 63;
    const int rg   = lane & 3;
    const int cg   = lane >> 2;
    const int qrow = w * 16 + rg * 4;   // base row-in-block for this lane

    const float* qbase = qp + ((size_t)bh * NSEQ + (size_t)tile * 64) * DH;
    const float* kbase = kp + (size_t)bh * NSEQ * DH;
    const float* vbase = vp + (size_t)bh * NSEQ * DH;

    // stage Q transposed (once per WG)
    #pragma unroll
    for (int it = 0; it < 4; ++it) {
        int f = tid + 256 * it;            // float4 index over 64 rows x 16 quads
        int r = f >> 4, qi = f & 15;
        float4 qv = *(const float4*)(qbase + (size_t)r * DH + qi * 4);
        Qt[(qi * 4 + 0) * 64 + r] = qv.x;
        Qt[(qi * 4 + 1) * 64 + r] = qv.y;
        Qt[(qi * 4 + 2) * 64 + r] = qv.z;
        Qt[(qi * 4 + 3) * 64 + r] = qv.w;
    }

    float o[4][4] = {};
    float m[4] = {-INFINITY, -INFINITY, -INFINITY, -INFINITY};
    float l[4] = {0.f, 0.f, 0.f, 0.f};

    for (int jt = 0; jt < NSEQ / 64; ++jt) {
        __syncthreads();   // previous iteration's readers of Kt/Vs are done
        // stage K (transposed) and V (row-major)
        #pragma unroll
        for (int it = 0; it < 4; ++it) {
            int f = tid + 256 * it;
            int r = f >> 4, qi = f & 15;
            const float* krow = kbase + ((size_t)jt * 64 + r) * DH + qi * 4;
            float4 kv = *(const float4*)krow;
            Kt[(qi * 4 + 0) * 64 + r] = kv.x;
            Kt[(qi * 4 + 1) * 64 + r] = kv.y;
            Kt[(qi * 4 + 2) * 64 + r] = kv.z;
            Kt[(qi * 4 + 3) * 64 + r] = kv.w;
            const float* vrow = vbase + ((size_t)jt * 64 + r) * DH + qi * 4;
            *(float4*)&Vs[r * DH + qi * 4] = *(const float4*)vrow;
        }
        __syncthreads();

        // scores: s[u][v] = sum_i Q[qrow+u][i] * K[cg*4+v][i]
        float s[4][4] = {};
        #pragma unroll 8
        for (int i = 0; i < DH; ++i) {
            float4 qv = *(const float4*)&Qt[i * 64 + qrow];
            float4 kv = *(const float4*)&Kt[i * 64 + (cg << 2)];
            float qa[4] = {qv.x, qv.y, qv.z, qv.w};
            float ka[4] = {kv.x, kv.y, kv.z, kv.w};
            #pragma unroll
            for (int u = 0; u < 4; ++u)
                #pragma unroll
                for (int v = 0; v < 4; ++v)
                    s[u][v] = fmaf(qa[u], ka[v], s[u][v]);
        }

        // online softmax (row stats replicated across the 16 cg lanes)
        float pr[4][4];
        #pragma unroll
        for (int u = 0; u < 4; ++u) {
            float mt = fmaxf(fmaxf(s[u][0], s[u][1]), fmaxf(s[u][2], s[u][3]));
            mt = fmaxf(mt, __shfl_xor(mt, 4));
            mt = fmaxf(mt, __shfl_xor(mt, 8));
            mt = fmaxf(mt, __shfl_xor(mt, 16));
            mt = fmaxf(mt, __shfl_xor(mt, 32));
            float mn = fmaxf(m[u], mt);
            float a  = __expf(m[u] - mn);
            m[u] = mn;
            float rs = 0.f;
            #pragma unroll
            for (int v = 0; v < 4; ++v) { pr[u][v] = __expf(s[u][v] - mn); rs += pr[u][v]; }
            rs += __shfl_xor(rs, 4);
            rs += __shfl_xor(rs, 8);
            rs += __shfl_xor(rs, 16);
            rs += __shfl_xor(rs, 32);
            l[u] = l[u] * a + rs;
            #pragma unroll
            for (int v = 0; v < 4; ++v) o[u][v] *= a;
        }

        // write P transposed: Ps[key][row]
        #pragma unroll
        for (int v = 0; v < 4; ++v) {
            float4 pv = make_float4(pr[0][v], pr[1][v], pr[2][v], pr[3][v]);
            *(float4*)&Ps[((cg << 2) + v) * 64 + qrow] = pv;
        }
        __syncthreads();

        // PV: o[u][v] += sum_j P[j][qrow+u] * V[j][cg*4+v]
        #pragma unroll 8
        for (int j = 0; j < 64; ++j) {
            float4 pv = *(const float4*)&Ps[j * 64 + qrow];
            float4 vv = *(const float4*)&Vs[j * DH + (cg << 2)];
            float pa[4] = {pv.x, pv.y, pv.z, pv.w};
            float va[4] = {vv.x, vv.y, vv.z, vv.w};
            #pragma unroll
            for (int u = 0; u < 4; ++u)
                #pragma unroll
                for (int v = 0; v < 4; ++v)
                    o[u][v] = fmaf(pa[u], va[v], o[u][v]);
        }
    }

    // epilogue: out[b][pos][h*64 + dim]
    const int b = bh >> 4, h = bh & 15;
    const int pos0 = tile * 64 + qrow;
    #pragma unroll
    for (int u = 0; u < 4; ++u) {
        float invl = 1.0f / l[u];
        float4 r4 = make_float4(o[u][0] * invl, o[u][1] * invl,
                                o[u][2] * invl, o[u][3] * invl);
        size_t oidx = ((size_t)b * NSEQ + (size_t)(pos0 + u)) * (NH * DH)
                    + (size_t)h * DH + (cg << 2);
        *(float4*)(out + oidx) = r4;
    }
}

extern "C" void kernel_launch(void* const* d_in, const int* in_sizes, int n_in,
                              void* d_out, int out_size, void* d_ws, size_t ws_size,
                              hipStream_t stream) {
    const float* q  = (const float*)d_in[0];
    const float* k  = (const float*)d_in[1];
    const float* v  = (const float*)d_in[2];
    const float* qs = (const float*)d_in[3];
    const float* ks = (const float*)d_in[4];
    float* outp = (float*)d_out;

    float* qp = (float*)d_ws;                       // 32*2048*64 f32 = 16 MB
    float* kp = qp + (size_t)BH * NSEQ * DH;        // next 16 MB

    dim3 pgrid(BH * NSEQ / 4);
    prep_kernel<<<pgrid, 256, 0, stream>>>(q, qs, qp, 0.125f);  // fold d^-0.5 into q
    prep_kernel<<<pgrid, 256, 0, stream>>>(k, ks, kp, 1.0f);

    dim3 agrid(NSEQ / 64, BH);
    attn_kernel<<<agrid, 256, 0, stream>>>(qp, kp, v, outp);
}

// Round 2
// 220.199 us; speedup vs baseline: 3.1502x; 3.1502x over previous
//
#include <hip/hip_runtime.h>
#include <math.h>

#define BH   32
#define NSEQ 2048
#define DH   64
#define NH   16
#define LOG2E 1.44269504088896f

typedef _Float16 f16x8 __attribute__((ext_vector_type(8)));
typedef float    f32x16v __attribute__((ext_vector_type(16)));

// ---------------- prep: l2norm * scale -> RoPE -> f16 (q also gets 0.125*log2e) ----
__global__ void prep_kernel(const float* __restrict__ in, const float* __restrict__ scale,
                            _Float16* __restrict__ out, float smul) {
    int row  = blockIdx.x * 4 + (threadIdx.x >> 6);
    int lane = threadIdx.x & 63;
    size_t base = (size_t)row * DH;
    float x = in[base + lane];
    float ss = x * x;
    #pragma unroll
    for (int off = 32; off > 0; off >>= 1) ss += __shfl_xor(ss, off);
    float inv = 1.0f / fmaxf(sqrtf(ss), 1e-12f);
    float t = x * inv * scale[lane];
    float partner = __shfl_xor(t, 32);
    float rot = (lane < 32) ? -partner : partner;
    int p = lane & 31;
    float inv_freq = powf(10000.0f, -(float)p / 32.0f);
    int pos = row & (NSEQ - 1);
    float theta = (float)pos * inv_freq;
    float sn, cs;
    sincosf(theta, &sn, &cs);
    out[base + lane] = (_Float16)((t * cs + rot * sn) * smul);
}

// ---------------- V: fp32 [bh][key][dim] -> f16 [bh][dim][key] ----------------
__global__ void vtrans_kernel(const float* __restrict__ v, _Float16* __restrict__ vt) {
    __shared__ _Float16 Ls[64 * 72];
    const int kt = blockIdx.x, bh = blockIdx.y;
    const int t = threadIdx.x;
    const int r = t >> 2, f = t & 3;
    const float* src = v + ((size_t)bh * NSEQ + kt * 64 + r) * DH + f * 16;
    float4 x0 = *(const float4*)(src + 0);
    float4 x1 = *(const float4*)(src + 4);
    float4 x2 = *(const float4*)(src + 8);
    float4 x3 = *(const float4*)(src + 12);
    union { _Float16 h[8]; uint4 u; } a, b;
    a.h[0]=(_Float16)x0.x; a.h[1]=(_Float16)x0.y; a.h[2]=(_Float16)x0.z; a.h[3]=(_Float16)x0.w;
    a.h[4]=(_Float16)x1.x; a.h[5]=(_Float16)x1.y; a.h[6]=(_Float16)x1.z; a.h[7]=(_Float16)x1.w;
    b.h[0]=(_Float16)x2.x; b.h[1]=(_Float16)x2.y; b.h[2]=(_Float16)x2.z; b.h[3]=(_Float16)x2.w;
    b.h[4]=(_Float16)x3.x; b.h[5]=(_Float16)x3.y; b.h[6]=(_Float16)x3.z; b.h[7]=(_Float16)x3.w;
    *(uint4*)&Ls[r * 72 + f * 16]     = a.u;
    *(uint4*)&Ls[r * 72 + f * 16 + 8] = b.u;
    __syncthreads();
    const int d = t >> 2;
    union { _Float16 h[8]; uint4 u; } o0, o1;
    #pragma unroll
    for (int i = 0; i < 8; ++i) o0.h[i] = Ls[(f * 16 + i) * 72 + d];
    #pragma unroll
    for (int i = 0; i < 8; ++i) o1.h[i] = Ls[(f * 16 + 8 + i) * 72 + d];
    _Float16* dst = vt + (size_t)bh * DH * NSEQ + (size_t)d * NSEQ + kt * 64 + f * 16;
    *(uint4*)(dst + 0) = o0.u;
    *(uint4*)(dst + 8) = o1.u;
}

// ---------------- flash attention: f16 MFMA 32x32x16, S^T/O^T form -------------
// WG = 128 threads (2 waves); q-block 128 rows, wave w owns rows w*64..w*64+63.
// S^T = K * Q^T  (A=K [key][dim] row-major, B=Q^T -> frags from Q row-major)
// C layout (m74/m101): col=lane&31 -> qrow; row=(r&3)+8*(r>>2)+4*(lane>>5) -> key.
// O^T = V^T * P^T (A=Vt [dim][key], B=P^T -> frags from P row-major [qrow][key]).
// All LDS strides = 72 halfs -> <=2-way bank aliasing. Double-buffered K/V.
__global__ __launch_bounds__(128) void attn_kernel(
    const _Float16* __restrict__ qh, const _Float16* __restrict__ kh,
    const _Float16* __restrict__ vth, float* __restrict__ out) {

    __shared__ _Float16 Ps[128 * 72];     // Q staged here first, then reused for P
    __shared__ _Float16 Ks[2][64 * 72];
    __shared__ _Float16 Vt[2][64 * 72];

    const int bh = blockIdx.y, qb = blockIdx.x;
    const int tid = threadIdx.x;
    const int w = tid >> 6, lane = tid & 63;
    const int c = lane & 31, hf = lane >> 5;

    const _Float16* qbase = qh + ((size_t)bh * NSEQ + qb * 128) * DH;
    const _Float16* kbase = kh + (size_t)bh * NSEQ * DH;
    const _Float16* vbase = vth + (size_t)bh * DH * NSEQ;

    // stage Q (128 rows x 64 dims) into Ps
    #pragma unroll
    for (int i = 0; i < 8; ++i) {
        int chunk = tid + 128 * i;
        int r = chunk >> 3, sg = chunk & 7;
        *(uint4*)&Ps[r * 72 + sg * 8] = *(const uint4*)(qbase + r * 64 + sg * 8);
    }
    // stage K/V tile 0
    #pragma unroll
    for (int i = 0; i < 4; ++i) {
        int chunk = tid + 128 * i;
        int r = chunk >> 3, sg = chunk & 7;
        *(uint4*)&Ks[0][r * 72 + sg * 8] = *(const uint4*)(kbase + r * 64 + sg * 8);
        *(uint4*)&Vt[0][r * 72 + sg * 8] = *(const uint4*)(vbase + (size_t)r * NSEQ + sg * 8);
    }
    __syncthreads();

    // hoist Q frags: B[k=dim][n=qrow] -> Q[qrow=w*64+nt*32+c][ks*16+hf*8+j]
    f16x8 qf[2][4];
    #pragma unroll
    for (int nt = 0; nt < 2; ++nt)
        #pragma unroll
        for (int ks = 0; ks < 4; ++ks)
            qf[nt][ks] = *(const f16x8*)&Ps[(w * 64 + nt * 32 + c) * 72 + ks * 16 + hf * 8];

    f32x16v o[2][2];
    #pragma unroll
    for (int a = 0; a < 2; ++a)
        #pragma unroll
        for (int bq = 0; bq < 2; ++bq)
            #pragma unroll
            for (int r = 0; r < 16; ++r) o[a][bq][r] = 0.f;
    float mrow[2] = {-INFINITY, -INFINITY};
    float lrow[2] = {0.f, 0.f};

    for (int jt = 0; jt < 32; ++jt) {
        const int cur = jt & 1;
        // prefetch next K/V tile into registers (hidden behind compute)
        uint4 kpre[4], vpre[4];
        if (jt + 1 < 32) {
            const _Float16* kn = kbase + (size_t)(jt + 1) * 64 * DH;
            const _Float16* vn = vbase + (jt + 1) * 64;
            #pragma unroll
            for (int i = 0; i < 4; ++i) {
                int chunk = tid + 128 * i;
                int r = chunk >> 3, sg = chunk & 7;
                kpre[i] = *(const uint4*)(kn + r * 64 + sg * 8);
                vpre[i] = *(const uint4*)(vn + (size_t)r * NSEQ + sg * 8);
            }
        }

        // S^T = K * Q^T
        f32x16v s[2][2];
        #pragma unroll
        for (int a = 0; a < 2; ++a)
            #pragma unroll
            for (int bq = 0; bq < 2; ++bq)
                #pragma unroll
                for (int r = 0; r < 16; ++r) s[a][bq][r] = 0.f;
        #pragma unroll
        for (int ks = 0; ks < 4; ++ks) {
            f16x8 ka0 = *(const f16x8*)&Ks[cur][(c) * 72      + ks * 16 + hf * 8];
            f16x8 ka1 = *(const f16x8*)&Ks[cur][(32 + c) * 72 + ks * 16 + hf * 8];
            s[0][0] = __builtin_amdgcn_mfma_f32_32x32x16_f16(ka0, qf[0][ks], s[0][0], 0, 0, 0);
            s[0][1] = __builtin_amdgcn_mfma_f32_32x32x16_f16(ka0, qf[1][ks], s[0][1], 0, 0, 0);
            s[1][0] = __builtin_amdgcn_mfma_f32_32x32x16_f16(ka1, qf[0][ks], s[1][0], 0, 0, 0);
            s[1][1] = __builtin_amdgcn_mfma_f32_32x32x16_f16(ka1, qf[1][ks], s[1][1], 0, 0, 0);
        }

        // online softmax (all 32 key-values of a qrow live in this lane + lane^32)
        #pragma unroll
        for (int nt = 0; nt < 2; ++nt) {
            float mv = s[0][nt][0];
            #pragma unroll
            for (int r = 1; r < 16; ++r) mv = fmaxf(mv, s[0][nt][r]);
            #pragma unroll
            for (int r = 0; r < 16; ++r) mv = fmaxf(mv, s[1][nt][r]);
            mv = fmaxf(mv, __shfl_xor(mv, 32));
            float mn = fmaxf(mrow[nt], mv);
            float al = exp2f(mrow[nt] - mn);
            mrow[nt] = mn;
            float rs = 0.f;
            #pragma unroll
            for (int mt = 0; mt < 2; ++mt)
                #pragma unroll
                for (int r = 0; r < 16; ++r) {
                    float pv = exp2f(s[mt][nt][r] - mn);
                    s[mt][nt][r] = pv;
                    rs += pv;
                }
            rs += __shfl_xor(rs, 32);
            lrow[nt] = lrow[nt] * al + rs;
            #pragma unroll
            for (int mt = 0; mt < 2; ++mt)
                #pragma unroll
                for (int r = 0; r < 16; ++r) o[mt][nt][r] *= al;
            // P -> LDS row-major [qrow][key]; key = mt*32 + 4*hf + (r&3) + 8*(r>>2)
            const int qr = w * 64 + nt * 32 + c;
            #pragma unroll
            for (int mt = 0; mt < 2; ++mt)
                #pragma unroll
                for (int g = 0; g < 4; ++g) {
                    union { _Float16 h[4]; uint2 u; } pk4;
                    pk4.h[0] = (_Float16)s[mt][nt][g * 4 + 0];
                    pk4.h[1] = (_Float16)s[mt][nt][g * 4 + 1];
                    pk4.h[2] = (_Float16)s[mt][nt][g * 4 + 2];
                    pk4.h[3] = (_Float16)s[mt][nt][g * 4 + 3];
                    *(uint2*)&Ps[qr * 72 + mt * 32 + g * 8 + hf * 4] = pk4.u;
                }
        }

        // O^T += V^T * P^T  (same-wave LDS RAW on Ps: in-order, compiler waits)
        #pragma unroll
        for (int ks = 0; ks < 4; ++ks) {
            f16x8 pb0 = *(const f16x8*)&Ps[(w * 64 + 0  + c) * 72 + ks * 16 + hf * 8];
            f16x8 pb1 = *(const f16x8*)&Ps[(w * 64 + 32 + c) * 72 + ks * 16 + hf * 8];
            f16x8 va0 = *(const f16x8*)&Vt[cur][(c) * 72      + ks * 16 + hf * 8];
            f16x8 va1 = *(const f16x8*)&Vt[cur][(32 + c) * 72 + ks * 16 + hf * 8];
            o[0][0] = __builtin_amdgcn_mfma_f32_32x32x16_f16(va0, pb0, o[0][0], 0, 0, 0);
            o[0][1] = __builtin_amdgcn_mfma_f32_32x32x16_f16(va0, pb1, o[0][1], 0, 0, 0);
            o[1][0] = __builtin_amdgcn_mfma_f32_32x32x16_f16(va1, pb0, o[1][0], 0, 0, 0);
            o[1][1] = __builtin_amdgcn_mfma_f32_32x32x16_f16(va1, pb1, o[1][1], 0, 0, 0);
        }

        // commit prefetched tile to the other buffer
        if (jt + 1 < 32) {
            #pragma unroll
            for (int i = 0; i < 4; ++i) {
                int chunk = tid + 128 * i;
                int r = chunk >> 3, sg = chunk & 7;
                *(uint4*)&Ks[1 - cur][r * 72 + sg * 8] = kpre[i];
                *(uint4*)&Vt[1 - cur][r * 72 + sg * 8] = vpre[i];
            }
        }
        __syncthreads();
    }

    // epilogue: out[b][pos][h*64 + dim], dim = mt*32 + 4*hf + (r&3) + 8*(r>>2)
    const int b = bh >> 4, h = bh & 15;
    #pragma unroll
    for (int nt = 0; nt < 2; ++nt) {
        float invl = 1.0f / lrow[nt];
        int pos = qb * 128 + w * 64 + nt * 32 + c;
        float* obase = out + ((size_t)b * NSEQ + pos) * (NH * DH) + h * DH;
        #pragma unroll
        for (int mt = 0; mt < 2; ++mt)
            #pragma unroll
            for (int g = 0; g < 4; ++g) {
                float4 r4 = make_float4(o[mt][nt][g * 4 + 0] * invl,
                                        o[mt][nt][g * 4 + 1] * invl,
                                        o[mt][nt][g * 4 + 2] * invl,
                                        o[mt][nt][g * 4 + 3] * invl);
                *(float4*)(obase + mt * 32 + g * 8 + hf * 4) = r4;
            }
    }
}

extern "C" void kernel_launch(void* const* d_in, const int* in_sizes, int n_in,
                              void* d_out, int out_size, void* d_ws, size_t ws_size,
                              hipStream_t stream) {
    const float* q  = (const float*)d_in[0];
    const float* k  = (const float*)d_in[1];
    const float* v  = (const float*)d_in[2];
    const float* qs = (const float*)d_in[3];
    const float* ks = (const float*)d_in[4];
    float* outp = (float*)d_out;

    _Float16* qh  = (_Float16*)d_ws;                    // 4 M halfs = 8 MB
    _Float16* kh  = qh + (size_t)BH * NSEQ * DH;
    _Float16* vth = kh + (size_t)BH * NSEQ * DH;        // [bh][dim][key]

    dim3 pgrid(BH * NSEQ / 4);
    prep_kernel<<<pgrid, 256, 0, stream>>>(q, qs, qh, 0.125f * LOG2E);
    prep_kernel<<<pgrid, 256, 0, stream>>>(k, ks, kh, 1.0f);

    vtrans_kernel<<<dim3(NSEQ / 64, BH), 256, 0, stream>>>(v, vth);

    attn_kernel<<<dim3(NSEQ / 128, BH), 128, 0, stream>>>(qh, kh, vth, outp);
}

// Round 4
// 154.051 us; speedup vs baseline: 4.5029x; 1.4294x over previous
//
#include <hip/hip_runtime.h>
#include <math.h>

#define BH   32
#define NSEQ 2048
#define DH   64
#define NH   16
#define LOG2E 1.44269504088896f

typedef _Float16 f16x8 __attribute__((ext_vector_type(8)));
typedef __fp16   fp16x2 __attribute__((ext_vector_type(2)));
typedef float    f32x16v __attribute__((ext_vector_type(16)));

#if __has_builtin(__builtin_amdgcn_exp2f)
#define EXP2F(x) __builtin_amdgcn_exp2f(x)
#else
#define EXP2F(x) exp2f(x)
#endif

static __device__ __forceinline__ unsigned packh_rne(float a, float b) {
    union { _Float16 h[2]; unsigned u; } x;
    x.h[0] = (_Float16)a; x.h[1] = (_Float16)b;
    return x.u;
}
static __device__ __forceinline__ unsigned pkrtz(float a, float b) {
    fp16x2 r = __builtin_amdgcn_cvt_pkrtz(a, b);
    return __builtin_bit_cast(unsigned, r);
}
#if __has_builtin(__builtin_amdgcn_perm)
#define PERM(a, b, s) __builtin_amdgcn_perm((a), (b), (s))
#else
static __device__ __forceinline__ unsigned PERM(unsigned a, unsigned b, unsigned s) {
    if (s == 0x05040100u) return (b & 0xffffu) | (a << 16);
    return (b >> 16) | (a & 0xffff0000u);
}
#endif

// lo = low halves of (r0,r1) -> [dim 2dp, keys j,j+1]; hi = high halves
static __device__ __forceinline__ void unpack_pairs(const unsigned* rr, uint4& lo, uint4& hi) {
    lo.x = PERM(rr[1], rr[0], 0x05040100u);  hi.x = PERM(rr[1], rr[0], 0x07060302u);
    lo.y = PERM(rr[3], rr[2], 0x05040100u);  hi.y = PERM(rr[3], rr[2], 0x07060302u);
    lo.z = PERM(rr[5], rr[4], 0x05040100u);  hi.z = PERM(rr[5], rr[4], 0x07060302u);
    lo.w = PERM(rr[7], rr[6], 0x05040100u);  hi.w = PERM(rr[7], rr[6], 0x07060302u);
}

// ---------------- rotary table: tab[pos][p] = (cos, sin), 2048 x 32 ----------
__global__ void freq_kernel(float2* __restrict__ tab) {
    int idx = blockIdx.x * 256 + threadIdx.x;   // 65536 entries
    int pos = idx >> 5, p = idx & 31;
    float inv_freq = powf(10000.0f, -(float)p / 32.0f);
    float sn, cs;
    sincosf((float)pos * inv_freq, &sn, &cs);
    tab[idx] = make_float2(cs, sn);
}

// ---------------- prep: l2norm * scale -> RoPE -> packed f16 pairs -----------
// half-wave (32 lanes) per row; lane handles dims 2c, 2c+1. Block 256 = 8 rows.
__global__ void prep_kernel(const float* __restrict__ in, const float* __restrict__ scale,
                            const float2* __restrict__ tab,
                            unsigned* __restrict__ out, float smul) {
    const int w = threadIdx.x >> 6, lane = threadIdx.x & 63;
    const int c = lane & 31, hfr = lane >> 5;
    const int row = blockIdx.x * 8 + w * 2 + hfr;
    const size_t base = (size_t)row * DH;
    float2 x2 = *(const float2*)(in + base + 2 * c);
    float ss = x2.x * x2.x + x2.y * x2.y;
    #pragma unroll
    for (int off = 16; off > 0; off >>= 1) ss += __shfl_xor(ss, off);
    float inv = 1.0f / fmaxf(sqrtf(ss), 1e-12f);
    float2 sc = *(const float2*)(scale + 2 * c);
    float t0 = x2.x * inv * sc.x;
    float t1 = x2.y * inv * sc.y;
    float p0 = __shfl_xor(t0, 16);
    float p1 = __shfl_xor(t1, 16);
    float r0 = (c < 16) ? -p0 : p0;
    float r1 = (c < 16) ? -p1 : p1;
    int pos = row & (NSEQ - 1);
    float4 cc = *(const float4*)((const float*)(tab + pos * 32) + ((2 * c) & 31) * 2);
    float o0 = (t0 * cc.x + r0 * cc.y) * smul;
    float o1 = (t1 * cc.z + r1 * cc.w) * smul;
    out[row * 32 + c] = packh_rne(o0, o1);
}

// ---------------- V: fp32 [bh][key][dim] -> u32 pairs [bh][dp=32][key] --------
// no LDS: each thread packs 16 dims of one row, stores 8 coalesced dword rows.
__global__ void vpack_kernel(const float* __restrict__ v, unsigned* __restrict__ vt2) {
    const int kt = blockIdx.x, bh = blockIdx.y;
    const int t = threadIdx.x;
    const int r = t & 63, ch = t >> 6;          // ch = dim chunk of 16
    const float* src = v + ((size_t)bh * NSEQ + kt * 64 + r) * DH + ch * 16;
    float4 a = *(const float4*)(src + 0);
    float4 b = *(const float4*)(src + 4);
    float4 c2 = *(const float4*)(src + 8);
    float4 d2 = *(const float4*)(src + 12);
    unsigned* dst = vt2 + ((size_t)bh * 32 + ch * 8) * NSEQ + kt * 64 + r;
    dst[0 * NSEQ] = packh_rne(a.x, a.y);
    dst[1 * NSEQ] = packh_rne(a.z, a.w);
    dst[2 * NSEQ] = packh_rne(b.x, b.y);
    dst[3 * NSEQ] = packh_rne(b.z, b.w);
    dst[4 * NSEQ] = packh_rne(c2.x, c2.y);
    dst[5 * NSEQ] = packh_rne(c2.z, c2.w);
    dst[6 * NSEQ] = packh_rne(d2.x, d2.y);
    dst[7 * NSEQ] = packh_rne(d2.z, d2.w);
}

// ---------------- flash attention: f16 MFMA 32x32x16, S^T/O^T, no P-LDS ------
// WG 256 = 4 waves; wave w owns qrows qb*128 + w*32 + c (c = lane&31).
// Fixed-max softmax (|s*log2e| <= 0.18 after l2norm: no overflow possible).
// P C-layout -> B-frag via pack + shfl_xor(32) + cndmask (no LDS round-trip).
__global__ __launch_bounds__(256, 2) void attn_kernel(
    const unsigned* __restrict__ qh, const unsigned* __restrict__ kh,
    const unsigned* __restrict__ vt2, float* __restrict__ out) {

    __shared__ _Float16 Ks[2][64 * 72];
    __shared__ _Float16 Vs[2][64 * 72];

    const int bh = blockIdx.y, qb = blockIdx.x;
    const int tid = threadIdx.x;
    const int w = tid >> 6, lane = tid & 63;
    const int c = lane & 31, hf = lane >> 5;

    const _Float16* qbase = (const _Float16*)qh + ((size_t)bh * NSEQ + qb * 128) * DH;
    const _Float16* kbase = (const _Float16*)kh + (size_t)bh * NSEQ * DH;
    const unsigned* vbase = vt2 + (size_t)bh * 32 * NSEQ;

    const int sdp = tid >> 3, skc = tid & 7;   // V staging: dim-pair, key-chunk

    // stage K/V tile 0
    #pragma unroll
    for (int i = 0; i < 2; ++i) {
        int chunk = tid + 256 * i;
        int r = chunk >> 3, sg = chunk & 7;
        *(uint4*)&Ks[0][r * 72 + sg * 8] = *(const uint4*)(kbase + r * 64 + sg * 8);
    }
    {
        const unsigned* vsrc = vbase + (size_t)sdp * NSEQ + skc * 8;
        unsigned rr[8];
        #pragma unroll
        for (int j = 0; j < 8; ++j) rr[j] = vsrc[j];
        uint4 lo, hi;
        unpack_pairs(rr, lo, hi);
        *(uint4*)&Vs[0][(2 * sdp) * 72 + skc * 8]     = lo;
        *(uint4*)&Vs[0][(2 * sdp + 1) * 72 + skc * 8] = hi;
    }

    // Q frags straight from global: B[k=dim][n=qrow]
    f16x8 qf[4];
    #pragma unroll
    for (int ks = 0; ks < 4; ++ks)
        qf[ks] = *(const f16x8*)(qbase + (w * 32 + c) * 64 + ks * 16 + hf * 8);

    f32x16v o[2];
    #pragma unroll
    for (int mt = 0; mt < 2; ++mt)
        #pragma unroll
        for (int r = 0; r < 16; ++r) o[mt][r] = 0.f;
    float lpart = 0.f;

    __syncthreads();

    for (int jt = 0; jt < 32; ++jt) {
        const int cur = jt & 1;
        uint4 kpre[2];
        unsigned vpre[8];
        if (jt + 1 < 32) {
            const _Float16* kn = kbase + (size_t)(jt + 1) * 64 * DH;
            #pragma unroll
            for (int i = 0; i < 2; ++i) {
                int chunk = tid + 256 * i;
                int r = chunk >> 3, sg = chunk & 7;
                kpre[i] = *(const uint4*)(kn + r * 64 + sg * 8);
            }
            const unsigned* vsrc = vbase + (size_t)sdp * NSEQ + (jt + 1) * 64 + skc * 8;
            #pragma unroll
            for (int j = 0; j < 8; ++j) vpre[j] = vsrc[j];
        }

        // S^T = K * Q^T : s[mt] covers keys mt*32..mt*32+31, qrow = c
        f32x16v s[2];
        #pragma unroll
        for (int mt = 0; mt < 2; ++mt)
            #pragma unroll
            for (int r = 0; r < 16; ++r) s[mt][r] = 0.f;
        #pragma unroll
        for (int ks = 0; ks < 4; ++ks) {
            f16x8 ka0 = *(const f16x8*)&Ks[cur][c * 72 + ks * 16 + hf * 8];
            f16x8 ka1 = *(const f16x8*)&Ks[cur][(32 + c) * 72 + ks * 16 + hf * 8];
            s[0] = __builtin_amdgcn_mfma_f32_32x32x16_f16(ka0, qf[ks], s[0], 0, 0, 0);
            s[1] = __builtin_amdgcn_mfma_f32_32x32x16_f16(ka1, qf[ks], s[1], 0, 0, 0);
        }

        // exp2 (no max subtraction) + running denominator
        #pragma unroll
        for (int mt = 0; mt < 2; ++mt)
            #pragma unroll
            for (int r = 0; r < 16; ++r) {
                float pv = EXP2F(s[mt][r]);
                s[mt][r] = pv;
                lpart += pv;
            }

        // O^T += V^T * P^T ; build B-frags in-register from C-layout
        #pragma unroll
        for (int mt = 0; mt < 2; ++mt) {
            #pragma unroll
            for (int kk = 0; kk < 2; ++kk) {
                unsigned P01 = pkrtz(s[mt][kk * 8 + 0], s[mt][kk * 8 + 1]);
                unsigned P23 = pkrtz(s[mt][kk * 8 + 2], s[mt][kk * 8 + 3]);
                unsigned P45 = pkrtz(s[mt][kk * 8 + 4], s[mt][kk * 8 + 5]);
                unsigned P67 = pkrtz(s[mt][kk * 8 + 6], s[mt][kk * 8 + 7]);
                unsigned x01 = (unsigned)__shfl_xor((int)P01, 32);
                unsigned x23 = (unsigned)__shfl_xor((int)P23, 32);
                unsigned x45 = (unsigned)__shfl_xor((int)P45, 32);
                unsigned x67 = (unsigned)__shfl_xor((int)P67, 32);
                union { unsigned u[4]; f16x8 v; } B;
                B.u[0] = hf ? x45 : P01;
                B.u[1] = hf ? x67 : P23;
                B.u[2] = hf ? P45 : x01;
                B.u[3] = hf ? P67 : x23;
                const int kc = mt * 2 + kk;
                f16x8 va0 = *(const f16x8*)&Vs[cur][c * 72 + kc * 16 + hf * 8];
                f16x8 va1 = *(const f16x8*)&Vs[cur][(32 + c) * 72 + kc * 16 + hf * 8];
                o[0] = __builtin_amdgcn_mfma_f32_32x32x16_f16(va0, B.v, o[0], 0, 0, 0);
                o[1] = __builtin_amdgcn_mfma_f32_32x32x16_f16(va1, B.v, o[1], 0, 0, 0);
            }
        }

        // commit prefetched tile
        if (jt + 1 < 32) {
            #pragma unroll
            for (int i = 0; i < 2; ++i) {
                int chunk = tid + 256 * i;
                int r = chunk >> 3, sg = chunk & 7;
                *(uint4*)&Ks[1 - cur][r * 72 + sg * 8] = kpre[i];
            }
            uint4 lo, hi;
            unpack_pairs(vpre, lo, hi);
            *(uint4*)&Vs[1 - cur][(2 * sdp) * 72 + skc * 8]     = lo;
            *(uint4*)&Vs[1 - cur][(2 * sdp + 1) * 72 + skc * 8] = hi;
        }
        __syncthreads();
    }

    // epilogue: dim = mt*32 + g*8 + hf*4 + (r&3)
    float ltot = lpart + __shfl_xor(lpart, 32);
    float invl = 1.0f / ltot;
    const int b = bh >> 4, h = bh & 15;
    const int pos = qb * 128 + w * 32 + c;
    float* obase = out + ((size_t)b * NSEQ + pos) * (NH * DH) + h * DH;
    #pragma unroll
    for (int mt = 0; mt < 2; ++mt)
        #pragma unroll
        for (int g = 0; g < 4; ++g) {
            float4 r4 = make_float4(o[mt][g * 4 + 0] * invl, o[mt][g * 4 + 1] * invl,
                                    o[mt][g * 4 + 2] * invl, o[mt][g * 4 + 3] * invl);
            *(float4*)(obase + mt * 32 + g * 8 + hf * 4) = r4;
        }
}

extern "C" void kernel_launch(void* const* d_in, const int* in_sizes, int n_in,
                              void* d_out, int out_size, void* d_ws, size_t ws_size,
                              hipStream_t stream) {
    const float* q  = (const float*)d_in[0];
    const float* k  = (const float*)d_in[1];
    const float* v  = (const float*)d_in[2];
    const float* qs = (const float*)d_in[3];
    const float* ks = (const float*)d_in[4];
    float* outp = (float*)d_out;

    unsigned* qh  = (unsigned*)d_ws;                       // 8 MB
    unsigned* kh  = qh + (size_t)BH * NSEQ * 32;           // 8 MB
    unsigned* vt2 = kh + (size_t)BH * NSEQ * 32;           // 8 MB
    float2*   tab = (float2*)(vt2 + (size_t)BH * NSEQ * 32);  // 512 KB

    freq_kernel<<<256, 256, 0, stream>>>(tab);
    prep_kernel<<<BH * NSEQ / 8, 256, 0, stream>>>(q, qs, tab, qh, 0.125f * LOG2E);
    prep_kernel<<<BH * NSEQ / 8, 256, 0, stream>>>(k, ks, tab, kh, 1.0f);
    vpack_kernel<<<dim3(NSEQ / 64, BH), 256, 0, stream>>>(v, vt2);
    attn_kernel<<<dim3(NSEQ / 128, BH), 256, 0, stream>>>(qh, kh, vt2, outp);
}